// Round 9
// baseline (133.757 us; speedup 1.0000x reference)
//
#include <hip/hip_runtime.h>

// SNN excitatory layer only (inhibitory layer never affects the returned
// spikes — the scan discards its carry).
//
// R8: 2 neurons per wave (ILP over TLP).
//  - Evidence R3..R7: bound by per-wave serial latency chain; in-order waves
//    with 2/SIMD can't fill stall holes. Two independent neuron chains per
//    wave share xq/ds_reads/staging/barrier and interleave through every
//    stall. 1024 waves = 1/SIMD, VGPR ceiling 256 via launch_bounds(256,1)
//    (R6's spill came from the (256,2) cap).
//  - spike branches wave-uniform via readfirstlane -> s_cbranch.
//  - tp pre-kernel: unroll 16 (batch loads per waitcnt).
//  - per-neuron arithmetic identical to R7 -> bit-exact spikes.

constexpr int T_STEPS = 128;
constexpr int N_IN    = 2048;
constexpr int N_EXC   = 2048;

__global__ __launch_bounds__(256)
void tp_precompute_kernel(const float* __restrict__ x, float* __restrict__ tp_ws) {
    const int j = blockIdx.x * blockDim.x + threadIdx.x;
    float tp = 0.f;
    #pragma unroll 16
    for (int t = 0; t < T_STEPS; ++t) {
        tp = fmaf(0.05f, x[t * N_IN + j] - tp, tp);
        tp_ws[t * N_IN + j] = tp;
    }
}

template <int CTRL, int RM>
__device__ __forceinline__ float dpp_add(float x) {
    int t = __builtin_amdgcn_update_dpp(0, __builtin_bit_cast(int, x),
                                        CTRL, RM, 0xF, true);
    return x + __builtin_bit_cast(float, t);
}

// Sum across 64 lanes; returns wave-uniform scalar (readlane 63 -> SGPR).
__device__ __forceinline__ float wave_sum64(float x) {
    x = dpp_add<0x111, 0xF>(x);   // row_shr:1
    x = dpp_add<0x112, 0xF>(x);   // row_shr:2
    x = dpp_add<0x114, 0xF>(x);   // row_shr:4
    x = dpp_add<0x118, 0xF>(x);   // row_shr:8
    x = dpp_add<0x142, 0xA>(x);   // row_bcast:15 -> rows 1,3
    x = dpp_add<0x143, 0xC>(x);   // row_bcast:31 -> rows 2,3
    return __builtin_bit_cast(float,
        __builtin_amdgcn_readlane(__builtin_bit_cast(int, x), 63));
}

__device__ __forceinline__ float clamp01(float x) {
    return __builtin_amdgcn_fmed3f(x, 0.f, 1.f);   // folds to clamp bit
}

__global__ __launch_bounds__(256, 1)
void snn_exc_kernel(const float* __restrict__ x,     // [T, N_IN]
                    const float* __restrict__ w0,    // [N_EXC, N_IN]
                    const float* __restrict__ tp_ws, // [T, N_IN]
                    float* __restrict__ out)         // [T, N_EXC]
{
    __shared__ __align__(16) float xs[2][N_IN];      // 16 KiB double buffer

    const int tid  = threadIdx.x;
    const int lane = tid & 63;
    const int wid  = tid >> 6;
    const int rowA = blockIdx.x * 8 + wid * 2;       // this wave: rows A, A+1

    // lane l owns columns j = m*256 + l*4 + {0..3}, m = 0..7, for BOTH rows
    float wA[32], wB[32];
    {
        const float4* ra = reinterpret_cast<const float4*>(w0 + (size_t)rowA * N_IN);
        const float4* rb = reinterpret_cast<const float4*>(w0 + (size_t)(rowA + 1) * N_IN);
        #pragma unroll
        for (int m = 0; m < 8; ++m) {
            float4 a = ra[m * 64 + lane];
            float4 b = rb[m * 64 + lane];
            wA[4*m+0] = a.x; wA[4*m+1] = a.y; wA[4*m+2] = a.z; wA[4*m+3] = a.w;
            wB[4*m+0] = b.x; wB[4*m+1] = b.y; wB[4*m+2] = b.z; wB[4*m+3] = b.w;
        }
    }

    // staging: wave wid covers floats [wid*512, wid*512+512) of each row
    const int stage_f = wid * 512 + lane * 4;
    float* outpA = out + rowA;
    float* outpB = out + rowA + 1;

    // prologue: row 0 -> xs[0]; row 1 -> pr
    {
        const float* s0 = x + stage_f;
        *reinterpret_cast<float4*>(&xs[0][stage_f])       = *reinterpret_cast<const float4*>(s0);
        *reinterpret_cast<float4*>(&xs[0][stage_f + 256]) = *reinterpret_cast<const float4*>(s0 + 256);
    }
    float4 pr0, pr1;
    {
        const float* s1 = x + N_IN + stage_f;
        pr0 = *reinterpret_cast<const float4*>(s1);
        pr1 = *reinterpret_cast<const float4*>(s1 + 256);
    }
    __syncthreads();

    float vA = 0.f, synA = 0.f, rhoA = 0.f, tpostA = 0.f;
    float vB = 0.f, synB = 0.f, rhoB = 0.f, tpostB = 0.f;

    for (int t = 0; t < T_STEPS; ++t) {
        // ---- (1) ds_read row t fragments (shared by both neurons) ----
        float4 xq[8];
        {
            const float4* xl = reinterpret_cast<const float4*>(xs[t & 1]);
            #pragma unroll
            for (int m = 0; m < 8; ++m) xq[m] = xl[m * 64 + lane];
        }

        // ---- (2) ds_write row t+1; (3) barrier publishes it ----
        {
            float* d = &xs[(t + 1) & 1][stage_f];
            *reinterpret_cast<float4*>(d)       = pr0;
            *reinterpret_cast<float4*>(d + 256) = pr1;
        }
        __syncthreads();

        // ---- (4) global-load row t+2 (full step of slack) ----
        {
            int tn = t + 2; if (tn > T_STEPS - 1) tn = T_STEPS - 1;
            const float* s = x + (size_t)tn * N_IN + stage_f;
            pr0 = *reinterpret_cast<const float4*>(s);
            pr1 = *reinterpret_cast<const float4*>(s + 256);
        }

        // ---- (5) scalar LIF, both neurons (spike known before the dot:
        //          v_dec uses the OLD synaptic current) ----
        const float vdA = fmaf(0.1f, synA - vA, vA);
        const bool  rfA = (rhoA > 0.f);
        const bool  skA = (vdA > 1.0f) && !rfA;
        vA    = (skA || rfA) ? 0.f : vdA;
        rhoA  = skA ? 5.0f : fmaxf(rhoA - 1.0f, 0.f);
        const float zA = skA ? 1.f : 0.f;
        tpostA = fmaf(0.05f, zA - tpostA, tpostA);
        const float c2A = 1e-3f * tpostA;

        const float vdB = fmaf(0.1f, synB - vB, vB);
        const bool  rfB = (rhoB > 0.f);
        const bool  skB = (vdB > 1.0f) && !rfB;
        vB    = (skB || rfB) ? 0.f : vdB;
        rhoB  = skB ? 5.0f : fmaxf(rhoB - 1.0f, 0.f);
        const float zB = skB ? 1.f : 0.f;
        tpostB = fmaf(0.05f, zB - tpostB, tpostB);
        const float c2B = 1e-3f * tpostB;

        if (lane == 0) { *outpA = zA; *outpB = zB; }
        outpA += N_EXC; outpB += N_EXC;

        // ---- (6) two independent dot products, interleaved by the
        //          scheduler (8 accumulator chains of depth 8) ----
        float a0 = 0.f, a1 = 0.f, a2 = 0.f, a3 = 0.f;
        float b0 = 0.f, b1 = 0.f, b2 = 0.f, b3 = 0.f;
        #pragma unroll
        for (int m = 0; m < 8; ++m) {
            a0 = fmaf(xq[m].x, wA[4*m+0], a0);
            b0 = fmaf(xq[m].x, wB[4*m+0], b0);
            a1 = fmaf(xq[m].y, wA[4*m+1], a1);
            b1 = fmaf(xq[m].y, wB[4*m+1], b1);
            a2 = fmaf(xq[m].z, wA[4*m+2], a2);
            b2 = fmaf(xq[m].z, wB[4*m+2], b2);
            a3 = fmaf(xq[m].w, wA[4*m+3], a3);
            b3 = fmaf(xq[m].w, wB[4*m+3], b3);
        }

        // ---- (7) STDP updates; wave-uniform branches via readfirstlane ----
        const int sAu = __builtin_amdgcn_readfirstlane((int)skA);
        const int sBu = __builtin_amdgcn_readfirstlane((int)skB);
        const float4* tq4 = reinterpret_cast<const float4*>(tp_ws + (size_t)t * N_IN) + lane;

        if (sAu) {
            #pragma unroll
            for (int m = 0; m < 8; ++m) {
                float4 tq = tq4[m * 64];
                wA[4*m+0] = clamp01(fmaf(1e-3f, tq.x, fmaf(-c2A, xq[m].x, wA[4*m+0])));
                wA[4*m+1] = clamp01(fmaf(1e-3f, tq.y, fmaf(-c2A, xq[m].y, wA[4*m+1])));
                wA[4*m+2] = clamp01(fmaf(1e-3f, tq.z, fmaf(-c2A, xq[m].z, wA[4*m+2])));
                wA[4*m+3] = clamp01(fmaf(1e-3f, tq.w, fmaf(-c2A, xq[m].w, wA[4*m+3])));
            }
        } else {
            #pragma unroll
            for (int m = 0; m < 8; ++m) {
                wA[4*m+0] = clamp01(fmaf(-c2A, xq[m].x, wA[4*m+0]));
                wA[4*m+1] = clamp01(fmaf(-c2A, xq[m].y, wA[4*m+1]));
                wA[4*m+2] = clamp01(fmaf(-c2A, xq[m].z, wA[4*m+2]));
                wA[4*m+3] = clamp01(fmaf(-c2A, xq[m].w, wA[4*m+3]));
            }
        }
        if (sBu) {
            #pragma unroll
            for (int m = 0; m < 8; ++m) {
                float4 tq = tq4[m * 64];
                wB[4*m+0] = clamp01(fmaf(1e-3f, tq.x, fmaf(-c2B, xq[m].x, wB[4*m+0])));
                wB[4*m+1] = clamp01(fmaf(1e-3f, tq.y, fmaf(-c2B, xq[m].y, wB[4*m+1])));
                wB[4*m+2] = clamp01(fmaf(1e-3f, tq.z, fmaf(-c2B, xq[m].z, wB[4*m+2])));
                wB[4*m+3] = clamp01(fmaf(1e-3f, tq.w, fmaf(-c2B, xq[m].w, wB[4*m+3])));
            }
        } else {
            #pragma unroll
            for (int m = 0; m < 8; ++m) {
                wB[4*m+0] = clamp01(fmaf(-c2B, xq[m].x, wB[4*m+0]));
                wB[4*m+1] = clamp01(fmaf(-c2B, xq[m].y, wB[4*m+1]));
                wB[4*m+2] = clamp01(fmaf(-c2B, xq[m].z, wB[4*m+2]));
                wB[4*m+3] = clamp01(fmaf(-c2B, xq[m].w, wB[4*m+3]));
            }
        }

        // ---- (8) two independent DPP reduces (consumed at step t+1) ----
        synA = fmaf(0.8f, synA, wave_sum64((a0 + a1) + (a2 + a3)));
        synB = fmaf(0.8f, synB, wave_sum64((b0 + b1) + (b2 + b3)));
    }
}

extern "C" void kernel_launch(void* const* d_in, const int* in_sizes, int n_in,
                              void* d_out, int out_size, void* d_ws, size_t ws_size,
                              hipStream_t stream) {
    const float* x  = (const float*)d_in[0];   // exc_currents [128, 2048] f32
    const float* w0 = (const float*)d_in[1];   // w_exc [2048, 2048] f32
    // d_in[2] (w_inh) unused: inhibitory layer does not affect the output
    float* out = (float*)d_out;                // spikes [128, 2048] f32

    float* tp_ws = (float*)d_ws;               // 1 MiB, ws_size is ample
    tp_precompute_kernel<<<N_IN / 256, 256, 0, stream>>>(x, tp_ws);

    dim3 grid(N_EXC / 8);                      // 256 blocks, 1 block/CU
    dim3 block(256);                           // 4 waves x 2 neurons each
    snn_exc_kernel<<<grid, block, 0, stream>>>(x, w0, tp_ws, out);
}